// Round 9
// baseline (108.149 us; speedup 1.0000x reference)
//
#include <hip/hip_runtime.h>
#include <cmath>

#define B_N 65536
#define C_N 128
#define D_N 32
#define K_N 10
#define EPS_F 1e-12f
#define SCALE_F (-0.72134752044448169f)   // -0.5 * log2(e)

#define NKK 46                    // 45 live K-steps + 1 zero pad (even count)
#define CHUNK_F16 4096            // per-step Q chunk: 4ct x 2hl x 64lane x 8 f16 = 8 KB
#define QF_N (NKK * CHUNK_F16)
#define YSTR 41                   // LDS y row stride (2 lanes/bank aliasing = free)

typedef _Float16 f16x8 __attribute__((ext_vector_type(8)));
typedef float    f32x16 __attribute__((ext_vector_type(16)));

// Step metadata, affine in (window w, row-pair r) order; kk>=45 is the zero-Q
// pad step (clamped to safe y offsets; prep writes Q=0 there).
__device__ __forceinline__ void mdkk(int kk, int& dA, int& e0) {
    if (kk >= 45) { dA = 0; e0 = 0; return; }
    int w = (kk >= 17) + (kk >= 30) + (kk >= 39) + (kk >= 44);
    int off = w == 0 ? 0 : (w == 1 ? 17 : (w == 2 ? 30 : (w == 3 ? 39 : 44)));
    int r = kk - off;
    dA = 2 * r;
    e0 = 2 * r + 8 * w;
}

// ---------------------------------------------------------------------------
// Fused prep: block = cluster c. Packs Q into the STAGING layout:
//   QF[kk*4096 + ct*1024 + hl*512 + (half*32 + (c&31))*8 + j]
// hl=0: fp16 hi, hl=1: fp16 lo. Feature (d = dA(kk)+half, e = e0(kk)+j),
// value SCALE * (2-off-diag folded) as before; 0 unless kk<45 & d<=e<=32.
// ---------------------------------------------------------------------------
__global__ __launch_bounds__(128) void k_prep(const float* __restrict__ S,
                                              const float* __restrict__ mu,
                                              const int* __restrict__ onehot,
                                              _Float16* __restrict__ QF,
                                              int* __restrict__ cls) {
    const int c = blockIdx.x;
    const int tid = threadIdx.x;
    __shared__ float sSm[D_N];
    __shared__ float st3;

    if (tid < D_N) {
        const float* Sr = S + (size_t)c * (D_N * D_N) + (size_t)tid * D_N;
        const float* mr = mu + (size_t)c * D_N;
        float a0 = 0.f, a1 = 0.f;
#pragma unroll
        for (int e = 0; e < D_N; e += 2) {
            a0 = fmaf(Sr[e + 0], mr[e + 0], a0);
            a1 = fmaf(Sr[e + 1], mr[e + 1], a1);
        }
        sSm[tid] = a0 + a1;
    }
    __syncthreads();
    if (tid == 0) {
        const float* mr = mu + (size_t)c * D_N;
        float a = 0.f;
#pragma unroll
        for (int d = 0; d < D_N; ++d) a = fmaf(mr[d], sSm[d], a);
        st3 = a;
        int cl = 0;
#pragma unroll
        for (int k = 0; k < K_N; ++k)
            if (onehot[c * K_N + k] != 0) cl = k;
        cls[c] = cl;
    }
    __syncthreads();

    if (tid < 2 * NKK) {
        const int kk   = tid >> 1;
        const int half = tid & 1;
        int dA, e0;
        mdkk(kk, dA, e0);
        const int d  = dA + half;
        const int ct = c >> 5;
        const size_t base = (size_t)kk * CHUNK_F16 + ct * 1024
                          + (size_t)(half * 32 + (c & 31)) * 8;
        const float* Sc = S + (size_t)c * (D_N * D_N);
        for (int j = 0; j < 8; ++j) {
            const int e = e0 + j;
            float q = 0.f;
            if (kk < 45 && d <= e && e <= 32) {
                float v;
                if (e < 32)      v = Sc[d * D_N + e] * (d == e ? 1.f : 2.f);
                else if (d < 32) v = -2.f * sSm[d];
                else             v = st3;          // d == e == 32
                q = SCALE_F * v;
            }
            _Float16 h = (_Float16)q;
            QF[base + j]       = h;                         // hi
            QF[base + 512 + j] = (_Float16)(q - (float)h);  // lo
        }
    }
}

// ---------------------------------------------------------------------------
// v7 helpers
// ---------------------------------------------------------------------------
__device__ __forceinline__ void gl_lds16(const void* g, void* l) {
    __builtin_amdgcn_global_load_lds(
        (const __attribute__((address_space(1))) unsigned int*)g,
        (__attribute__((address_space(3))) unsigned int*)l, 16, 0, 0);
}

// Stage one 8 KB chunk: 4 waves x 2 issues x (64 lanes x 16 B). LDS dest is
// wave-uniform base (+ lane*16 by HW); global src is per-lane and linear.
__device__ __forceinline__ void stage_chunk(const _Float16* __restrict__ QF,
                                            _Float16* __restrict__ dst,
                                            int chunk, int wid, int lane) {
#pragma unroll
    for (int i = 0; i < 2; ++i) {
        const int slot = i * 4 + wid;
        gl_lds16(QF + (size_t)chunk * CHUNK_F16 + slot * 512 + lane * 8,
                 dst + slot * 512);
    }
}

// Counted-vmcnt phase sync (T3/T4, m201 pattern): each wave verifies its OWN
// 2 loads for the chunk about to be consumed have landed (vmcnt<=VM leaves
// newer chunks in flight), then the barrier makes that a block-wide
// guarantee. sched_barrier(0) pins the following ds_reads after the barrier
// (rule #18: "memory" clobber alone doesn't order reg-only/LDS ops).
template <int VM>
__device__ __forceinline__ void sync_chunk() {
    if constexpr (VM == 4)      asm volatile("s_waitcnt vmcnt(4)" ::: "memory");
    else if constexpr (VM == 2) asm volatile("s_waitcnt vmcnt(2)" ::: "memory");
    else                        asm volatile("s_waitcnt vmcnt(0)" ::: "memory");
    __builtin_amdgcn_s_barrier();
    __builtin_amdgcn_sched_barrier(0);
}

__device__ __forceinline__ void ldy(const float* sy, int ybase, int hioff,
                                    int kk, float& yd, float (&yw)[8]) {
    int dA, e0;
    mdkk(kk, dA, e0);
    yd = sy[ybase + dA + hioff];
#pragma unroll
    for (int j = 0; j < 8; ++j) yw[j] = sy[ybase + e0 + j];
}

__device__ __forceinline__ void step_compute(const _Float16* __restrict__ buf,
                                             int lane, float yd, const float (&yw)[8],
                                             f32x16 (&acc)[4]) {
    const f16x8* qb = (const f16x8*)buf;     // [ct][hl][lane] 16B frags, literal offs
    f16x8 qh[4], ql[4];
#pragma unroll
    for (int ct = 0; ct < 4; ++ct) {
        qh[ct] = qb[ct * 128 + lane];
        ql[ct] = qb[ct * 128 + 64 + lane];
    }
    // phi build via packed RTZ converts (vector result type is __fp16-based;
    // element-wise access converts scalar-wise).
    f16x8 ph, pl;
#pragma unroll
    for (int j = 0; j < 8; j += 2) {
        float f0 = yd * yw[j], f1 = yd * yw[j + 1];
        auto h2 = __builtin_amdgcn_cvt_pkrtz(f0, f1);
        float r0 = f0 - (float)h2[0];
        float r1 = f1 - (float)h2[1];
        auto l2 = __builtin_amdgcn_cvt_pkrtz(r0, r1);
        ph[j] = h2[0]; ph[j + 1] = h2[1];
        pl[j] = l2[0]; pl[j + 1] = l2[1];
    }
    // same section order as v5/v6 (keep accumulation order == keep numerics)
    __builtin_amdgcn_s_setprio(1);
#pragma unroll
    for (int ct = 0; ct < 4; ++ct)
        acc[ct] = __builtin_amdgcn_mfma_f32_32x32x16_f16(qh[ct], ph, acc[ct], 0, 0, 0);
#pragma unroll
    for (int ct = 0; ct < 4; ++ct)
        acc[ct] = __builtin_amdgcn_mfma_f32_32x32x16_f16(ql[ct], ph, acc[ct], 0, 0, 0);
#pragma unroll
    for (int ct = 0; ct < 4; ++ct)
        acc[ct] = __builtin_amdgcn_mfma_f32_32x32x16_f16(qh[ct], pl, acc[ct], 0, 0, 0);
    __builtin_amdgcn_s_setprio(0);
}

// ---------------------------------------------------------------------------
// Main v7: v6 + counted-vmcnt pipeline. 4-deep LDS chunk ring; per step:
// {ldy next || s_waitcnt vmcnt(4); s_barrier; sched_barrier(0); issue stage
// t+3; compute step t}. vmcnt never drains to 0 in the main loop (v6's
// __syncthreads drained the one-step-old stage -> ~200cyc stall per step =
// the measured 46%-LDS-utilization gap). Ring safety: a wave stages slot
// (t+3)&3 = (t-1)&3 only after the step-t barrier, which all waves reach
// only after finishing step t-1's reads of that slot. Tail: peeled steps
// with vmcnt(2)/vmcnt(0). Epilogue unchanged.
// ---------------------------------------------------------------------------
__global__ __launch_bounds__(256, 2) void k_mainv7(const float* __restrict__ data,
                                                   const _Float16* __restrict__ QF,
                                                   const int* __restrict__ clsp,
                                                   float* __restrict__ out) {
    const int tid  = threadIdx.x;
    const int lane = tid & 63;
    const int wid  = tid >> 6;
    const int b0w  = blockIdx.x * 128 + wid * 32;   // wave's first row
    const int col  = lane & 31;
    const bool hi  = lane >= 32;

    __shared__ float sy[256 * YSTR + 64];
    __shared__ alignas(16) _Float16 qbuf[4][CHUNK_F16];
    __shared__ int lcls[C_N];
    if (tid < C_N) lcls[tid] = clsp[tid];

    const int ybase = tid * YSTR;
    {
        const float4* p0 = (const float4*)(data + (size_t)(b0w + col) * D_N);
#pragma unroll
        for (int i = 0; i < 8; ++i) {
            float4 v = p0[i];
            sy[ybase + 4 * i + 0] = v.x;
            sy[ybase + 4 * i + 1] = v.y;
            sy[ybase + 4 * i + 2] = v.z;
            sy[ybase + 4 * i + 3] = v.w;
        }
        sy[ybase + 32] = 1.f;                        // homogeneous slot
#pragma unroll
        for (int i = 33; i < YSTR; ++i) sy[ybase + i] = 0.f;
        if (tid < 64) sy[256 * YSTR + tid] = 0.f;    // safety pad
    }

    f32x16 acc[4];
#pragma unroll
    for (int ct = 0; ct < 4; ++ct)
#pragma unroll
        for (int g = 0; g < 16; ++g) acc[ct][g] = 0.f;

    // prologue: stage chunks 0..2; full-drain barrier (once) also covers sy
    stage_chunk(QF, &qbuf[0][0], 0, wid, lane);
    stage_chunk(QF, &qbuf[1][0], 1, wid, lane);
    stage_chunk(QF, &qbuf[2][0], 2, wid, lane);
    __syncthreads();

    const int hioff = hi ? 1 : 0;
    float ydA, ywA[8], ydB, ywB[8];
    ldy(sy, ybase, hioff, 0, ydA, ywA);

#pragma clang loop unroll(disable)
    for (int t = 0; t < NKK - 2; t += 2) {
        // ---- step t (slot t&3, y in A) ----
        ldy(sy, ybase, hioff, t + 1, ydB, ywB);
        sync_chunk<4>();
        if (t + 3 < NKK) stage_chunk(QF, &qbuf[(t + 3) & 3][0], t + 3, wid, lane);
        step_compute(&qbuf[t & 3][0], lane, ydA, ywA, acc);
        // ---- step t+1 (slot (t+1)&3, y in B) ----
        ldy(sy, ybase, hioff, t + 2, ydA, ywA);
        sync_chunk<4>();
        if (t + 4 < NKK) stage_chunk(QF, &qbuf[(t + 4) & 3][0], t + 4, wid, lane);
        step_compute(&qbuf[(t + 1) & 3][0], lane, ydB, ywB, acc);
    }
    // ---- peeled tail: steps NKK-2, NKK-1 (y(NKK-2) is in A) ----
    ldy(sy, ybase, hioff, NKK - 1, ydB, ywB);
    sync_chunk<2>();
    step_compute(&qbuf[(NKK - 2) & 3][0], lane, ydA, ywA, acc);
    sync_chunk<0>();
    step_compute(&qbuf[(NKK - 1) & 3][0], lane, ydB, ywB, acc);

    // ---------------- fused finalize (Gamma stays in registers) --------------
    // C/D layout (HW-verified): col=lane&31 (b), c = ct*32+(g&3)+8*(g>>2)+4*hi
    const float hoff = hi ? 4.f : 0.f;
    const int* lc = lcls + (hi ? 4 : 0);
    float sum = 0.f, gmax = -1.f, gcf = 0.f;
    float a0 = 0, a1 = 0, a2 = 0, a3 = 0, a4 = 0, a5 = 0, a6 = 0, a7 = 0, a8 = 0, a9 = 0;
#pragma unroll
    for (int ct = 0; ct < 4; ++ct) {
        float psum = 0.f;
#pragma unroll
        for (int g = 0; g < 16; ++g) {
            float v = acc[ct][g];
            float gm;
            asm("v_exp_f32 %0, %1" : "=v"(gm) : "v"(v));   // 2^v = exp(-0.5 d2)
            const int cbase = ct * 32 + (g & 3) + 8 * (g >> 2);
            int cl = lc[cbase];                 // LDS broadcast read
            psum += gm;
            float cf = (float)cbase + hoff;
            if (gm > gmax) { gmax = gm; gcf = cf; }   // lane scans c ascending
            a0 += (cl == 0) ? gm : 0.f;
            a1 += (cl == 1) ? gm : 0.f;
            a2 += (cl == 2) ? gm : 0.f;
            a3 += (cl == 3) ? gm : 0.f;
            a4 += (cl == 4) ? gm : 0.f;
            a5 += (cl == 5) ? gm : 0.f;
            a6 += (cl == 6) ? gm : 0.f;
            a7 += (cl == 7) ? gm : 0.f;
            a8 += (cl == 8) ? gm : 0.f;
            a9 += (cl == 9) ? gm : 0.f;
        }
        sum += psum;
    }

    // combine lane pair (l, l+32): same b-row, complementary c halves
    sum += __shfl_xor(sum, 32, 64);
    {
        float om = __shfl_xor(gmax, 32, 64);
        float oc = __shfl_xor(gcf, 32, 64);
        bool take = (om > gmax) || (om == gmax && oc < gcf);  // first-index tie
        if (take) { gmax = om; gcf = oc; }
    }
    a0 += __shfl_xor(a0, 32, 64);
    a1 += __shfl_xor(a1, 32, 64);
    a2 += __shfl_xor(a2, 32, 64);
    a3 += __shfl_xor(a3, 32, 64);
    a4 += __shfl_xor(a4, 32, 64);
    a5 += __shfl_xor(a5, 32, 64);
    a6 += __shfl_xor(a6, 32, 64);
    a7 += __shfl_xor(a7, 32, 64);
    a8 += __shfl_xor(a8, 32, 64);
    a9 += __shfl_xor(a9, 32, 64);

    if (!hi) {
        const int b = b0w + col;
        float inv = 1.0f / (sum + EPS_F);
        float ls[K_N] = {a0 * inv, a1 * inv, a2 * inv, a3 * inv, a4 * inv,
                         a5 * inv, a6 * inv, a7 * inv, a8 * inv, a9 * inv};
        float best = -1.f;
        int bk = 0;
#pragma unroll
        for (int k = 0; k < K_N; ++k)
            if (ls[k] > best) { best = ls[k]; bk = k; }
        float2* o2 = (float2*)(out + (size_t)b * K_N);   // b*40B is 8B-aligned
#pragma unroll
        for (int k2 = 0; k2 < K_N / 2; ++k2)
            o2[k2] = make_float2(ls[2 * k2], ls[2 * k2 + 1]);
        out[(size_t)B_N * K_N + b] = (float)bk;
        out[(size_t)B_N * K_N + B_N + b] = gcf;
    }
}

// ---------------------------------------------------------------------------
extern "C" void kernel_launch(void* const* d_in, const int* in_sizes, int n_in,
                              void* d_out, int out_size, void* d_ws, size_t ws_size,
                              hipStream_t stream) {
    const float* data   = (const float*)d_in[0];   // [B, D]
    const float* mu     = (const float*)d_in[1];   // [C, D]
    const float* S      = (const float*)d_in[2];   // [C, D, D]
    const int*   onehot = (const int*)d_in[3];     // [C, K]
    float* out = (float*)d_out;

    // ws: QF [QF_N f16] | cls [C]
    _Float16* QF  = (_Float16*)d_ws;
    int*      cls = (int*)(QF + QF_N);

    hipLaunchKernelGGL(k_prep, dim3(C_N), dim3(128), 0, stream,
                       S, mu, onehot, QF, cls);
    hipLaunchKernelGGL(k_mainv7, dim3(B_N / 128), dim3(256), 0, stream,
                       data, QF, cls, out);
}